// Round 3
// baseline (57.998 us; speedup 1.0000x reference)
//
#include <hip/hip_runtime.h>

#define NG 20000
#define NB 1024

typedef float v4f __attribute__((ext_vector_type(4)));

constexpr int THREADS = 256;
constexpr int GPT = 4;                        // genes per thread (both techs)
constexpr int GPB = THREADS * GPT;            // 1024 genes per block
constexpr int NGB = (NG + GPB - 1) / GPB;     // 20 gene blocks (tail in gb=19)
constexpr int BB  = 16;                       // batches per block
constexpr int NBB = NB / BB;                  // 64 batch blocks
constexpr int BB_PER_XCD = NBB / 8;           // 8 batch-chunks per XCD

// Each thread owns 4 consecutive genes, BOTH techs, params in registers
// (~116 floats). Per batch: two 16B/lane NT loads (1KB contiguous per wave
// per tech), full-wave 16B/lane NT store. No cross-lane exchange at all.
__global__ __launch_bounds__(THREADS, 3)
void cgm_kernel(const float* __restrict__ x,
                const float* __restrict__ w1,
                const float* __restrict__ b1,
                const float* __restrict__ w2,
                const float* __restrict__ b2,
                const float* __restrict__ wg,
                const float* __restrict__ bg,
                float* __restrict__ out)
{
    // XCD mapping: each XCD owns 8 batch-chunks x all 20 gene-chunks.
    // Consecutive j on an XCD sweep gene-chunks of one batch stripe.
    const int bid = (int)blockIdx.x;          // 0..1279
    const int xcd = bid & 7;
    const int j   = bid >> 3;                 // 0..159
    const int gb  = j % NGB;                  // 0..19
    const int bb  = xcd * BB_PER_XCD + j / NGB;

    const int gbase = gb * GPB + (int)threadIdx.x * GPT;
    if (gbase >= NG) return;                  // tail threads in gb==19

    // ---- per-thread params in registers (both techs, 4 genes) ----
    v4f W1[2][4], B1[2][4], W2[2][4];
    float B2v[2][4];
    #pragma unroll
    for (int t = 0; t < 2; ++t) {
        const size_t r0 = (size_t)t * NG + (size_t)gbase;
        #pragma unroll
        for (int g = 0; g < 4; ++g) {
            W1[t][g]  = *(const v4f*)(w1 + (r0 + g) * 4);
            B1[t][g]  = *(const v4f*)(b1 + (r0 + g) * 4);
            W2[t][g]  = *(const v4f*)(w2 + (r0 + g) * 4);
            B2v[t][g] = b2[r0 + g];
        }
    }
    // wg[g][2] pairs for 4 genes: (g0t0,g0t1,g1t0,g1t1), (g2t0,g2t1,g3t0,g3t1)
    const v4f wgA = *(const v4f*)(wg + (size_t)gbase * 2);
    const v4f wgB = *(const v4f*)(wg + (size_t)gbase * 2 + 4);
    const v4f bgv = *(const v4f*)(bg + gbase);

    const float* xb0 = x + (size_t)gbase;          // tech0 column base
    float*       ob  = out + (size_t)gbase;

    const int b_lo = bb * BB;
    #pragma unroll 4
    for (int bi = 0; bi < BB; ++bi) {
        const size_t b = (size_t)(b_lo + bi);
        const float* xr = xb0 + b * (2 * NG);
        const v4f x0 = __builtin_nontemporal_load((const v4f*)xr);        // tech0
        const v4f x1 = __builtin_nontemporal_load((const v4f*)(xr + NG)); // tech1

        float s[2][4];
        #pragma unroll
        for (int t = 0; t < 2; ++t) {
            const v4f xv = (t == 0) ? x0 : x1;
            #pragma unroll
            for (int g = 0; g < 4; ++g) {
                const float v = xv[g];
                float h, acc = 0.f;
                h = fmaxf(fmaf(v, W1[t][g].x, B1[t][g].x), 0.f); acc = fmaf(h, W2[t][g].x, acc);
                h = fmaxf(fmaf(v, W1[t][g].y, B1[t][g].y), 0.f); acc = fmaf(h, W2[t][g].y, acc);
                h = fmaxf(fmaf(v, W1[t][g].z, B1[t][g].z), 0.f); acc = fmaf(h, W2[t][g].z, acc);
                h = fmaxf(fmaf(v, W1[t][g].w, B1[t][g].w), 0.f); acc = fmaf(h, W2[t][g].w, acc);
                s[t][g] = fmaxf(acc + B2v[t][g], 0.f);
            }
        }

        v4f o;
        o.x = fmaxf(fmaf(s[0][0], wgA.x, fmaf(s[1][0], wgA.y, bgv.x)), 0.f);
        o.y = fmaxf(fmaf(s[0][1], wgA.z, fmaf(s[1][1], wgA.w, bgv.y)), 0.f);
        o.z = fmaxf(fmaf(s[0][2], wgB.x, fmaf(s[1][2], wgB.y, bgv.z)), 0.f);
        o.w = fmaxf(fmaf(s[0][3], wgB.z, fmaf(s[1][3], wgB.w, bgv.w)), 0.f);
        __builtin_nontemporal_store(o, (v4f*)(ob + b * NG));
    }
}

extern "C" void kernel_launch(void* const* d_in, const int* in_sizes, int n_in,
                              void* d_out, int out_size, void* d_ws, size_t ws_size,
                              hipStream_t stream) {
    const float* x  = (const float*)d_in[0];
    const float* w1 = (const float*)d_in[1];
    const float* b1 = (const float*)d_in[2];
    const float* w2 = (const float*)d_in[3];
    const float* b2 = (const float*)d_in[4];
    const float* wg = (const float*)d_in[5];
    const float* bg = (const float*)d_in[6];
    float* out = (float*)d_out;

    dim3 grid(NGB * NBB);   // 20 * 64 = 1280 blocks
    cgm_kernel<<<grid, THREADS, 0, stream>>>(x, w1, b1, w2, b2, wg, bg, out);
}